// Round 1
// baseline (437.378 us; speedup 1.0000x reference)
//
#include <hip/hip_runtime.h>

typedef __bf16 bf16;
typedef __bf16 bf16x8 __attribute__((ext_vector_type(8)));
typedef float f32x4 __attribute__((ext_vector_type(4)));

#define MFMA16(a, b, c) __builtin_amdgcn_mfma_f32_16x16x32_bf16((a), (b), (c), 0, 0, 0)

// ---------------- elementwise f32 -> bf16 (8 per thread) ----------------
__global__ __launch_bounds__(256) void k_convX(const float* __restrict__ in, bf16* __restrict__ out) {
    size_t i = ((size_t)blockIdx.x * 256 + threadIdx.x) * 8;
    float4 a = *(const float4*)(in + i);
    float4 b = *(const float4*)(in + i + 4);
    bf16 e[8];
    e[0] = (bf16)a.x; e[1] = (bf16)a.y; e[2] = (bf16)a.z; e[3] = (bf16)a.w;
    e[4] = (bf16)b.x; e[5] = (bf16)b.y; e[6] = (bf16)b.z; e[7] = (bf16)b.w;
    uint4 u; __builtin_memcpy(&u, e, 16);
    *(uint4*)(out + i) = u;
}

// ------------- transpose+convert: in f32 [R][C] -> out bf16 [C][R] -------------
__global__ __launch_bounds__(256) void k_tconv(const float* __restrict__ in, bf16* __restrict__ out,
                                               int R, int C) {
    __shared__ float tile[64][65];
    int bx = blockIdx.x, by = blockIdx.y;   // bx over C/64, by over R/64
    int t = threadIdx.x;
    for (int i = 0; i < 16; ++i) {
        int e = i * 256 + t; int r = e >> 6, c = e & 63;
        tile[r][c] = in[(size_t)(by * 64 + r) * C + bx * 64 + c];
    }
    __syncthreads();
    for (int i = 0; i < 16; ++i) {
        int e = i * 256 + t; int r = e >> 6, c = e & 63;
        out[(size_t)(bx * 64 + r) * R + by * 64 + c] = (bf16)tile[c][r];
    }
}

// ------------- V [H][S][64] -> Vt [H][64][S] -------------
__global__ __launch_bounds__(256) void k_vtrans(const bf16* __restrict__ V, bf16* __restrict__ Vt) {
    __shared__ bf16 tl[64][68];   // pad to 136B rows: 2-way max on reads
    int t0 = blockIdx.x * 64;
    int h = blockIdx.y;
    int t = threadIdx.x;
    const bf16* Vh = V + (size_t)h * 4096 * 64;
    #pragma unroll
    for (int i = 0; i < 2; ++i) {
        int c = i * 256 + t; int row = c >> 3, ch = c & 7;
        uint4 v = *(const uint4*)(Vh + (size_t)(t0 + row) * 64 + ch * 8);
        bf16 e[8]; __builtin_memcpy(e, &v, 16);
        #pragma unroll
        for (int j = 0; j < 8; ++j) tl[row][ch * 8 + j] = e[j];
    }
    __syncthreads();
    bf16* Vth = Vt + (size_t)h * 64 * 4096;
    #pragma unroll
    for (int i = 0; i < 2; ++i) {
        int c = i * 256 + t; int d = c >> 3, tch = c & 7;
        bf16 e[8];
        #pragma unroll
        for (int j = 0; j < 8; ++j) e[j] = tl[tch * 8 + j][d];
        uint4 u; __builtin_memcpy(&u, e, 16);
        *(uint4*)(Vth + (size_t)d * 4096 + t0 + tch * 8) = u;
    }
}

// ------------- 128x128 bf16 GEMM core: A [*,Kd] rm, Bt [*,Kd] rm, BK=64, XOR-swizzled LDS -------------
__device__ __forceinline__ void gemm128_core(const bf16* __restrict__ A, const bf16* __restrict__ Bt,
                                             int r0, int c0, int Kd, char* As, char* Bs,
                                             f32x4 (&acc)[4][4]) {
    int t = threadIdx.x, l = t & 63, w = t >> 6;
    int g = l >> 4, li = l & 15;
    int wr = w >> 1, wc = w & 1;
    for (int k0 = 0; k0 < Kd; k0 += 64) {
        uint4 ra[4], rb[4];
        #pragma unroll
        for (int i = 0; i < 4; ++i) {
            int c = i * 256 + t; int row = c >> 3, ch = c & 7;
            ra[i] = *(const uint4*)(A  + (size_t)(r0 + row) * Kd + k0 + ch * 8);
            rb[i] = *(const uint4*)(Bt + (size_t)(c0 + row) * Kd + k0 + ch * 8);
        }
        __syncthreads();
        #pragma unroll
        for (int i = 0; i < 4; ++i) {
            int c = i * 256 + t; int row = c >> 3, ch = c & 7;
            int off = (row * 128 + ch * 16) ^ ((row & 7) << 4);
            *(uint4*)(As + off) = ra[i];
            *(uint4*)(Bs + off) = rb[i];
        }
        __syncthreads();
        #pragma unroll
        for (int kk = 0; kk < 2; ++kk) {
            bf16x8 af[4], bfr[4];
            #pragma unroll
            for (int m = 0; m < 4; ++m) {
                int row = wr * 64 + m * 16 + li;
                af[m] = *(const bf16x8*)(As + ((row * 128 + kk * 64 + g * 16) ^ ((row & 7) << 4)));
            }
            #pragma unroll
            for (int n = 0; n < 4; ++n) {
                int row = wc * 64 + n * 16 + li;
                bfr[n] = *(const bf16x8*)(Bs + ((row * 128 + kk * 64 + g * 16) ^ ((row & 7) << 4)));
            }
            #pragma unroll
            for (int m = 0; m < 4; ++m)
                #pragma unroll
                for (int n = 0; n < 4; ++n)
                    acc[m][n] = MFMA16(af[m], bfr[n], acc[m][n]);
        }
    }
}

// ------------- GEMM1: qkv = Xb @ WqkvT^T + bqkv; scatter to Q(scaled)/K/V [H][S][64] -------------
__global__ __launch_bounds__(256) void k_gemm_qkv(const bf16* __restrict__ Xb, const bf16* __restrict__ WqkvT,
                                                  const float* __restrict__ bqkv,
                                                  bf16* __restrict__ Q, bf16* __restrict__ K,
                                                  bf16* __restrict__ V) {
    __shared__ __align__(16) char As[16384];
    __shared__ __align__(16) char Bs[16384];
    int r0 = blockIdx.y * 128, c0 = blockIdx.x * 128;
    f32x4 acc[4][4] = {};
    gemm128_core(Xb, WqkvT, r0, c0, 1024, As, Bs, acc);
    int t = threadIdx.x, l = t & 63, w = t >> 6;
    int g = l >> 4, li = l & 15;
    int wr = w >> 1, wc = w & 1;
    int colbase = c0 + wc * 64;            // multiple of 64 => one head per wave-column
    int sec = colbase >> 10;               // 0=Q 1=K 2=V
    int head = (colbase & 1023) >> 6;
    bf16* dst = (sec == 0) ? Q : (sec == 1) ? K : V;
    float scale = (sec == 0) ? 0.125f : 1.0f;   // 1/sqrt(64) folded into Q
    #pragma unroll
    for (int m = 0; m < 4; ++m)
        #pragma unroll
        for (int n = 0; n < 4; ++n) {
            int hd = n * 16 + li;
            float bias = bqkv[colbase + hd];
            #pragma unroll
            for (int r = 0; r < 4; ++r) {
                int row = r0 + wr * 64 + m * 16 + g * 4 + r;
                dst[(size_t)(head * 4096 + row) * 64 + hd] = (bf16)((acc[m][n][r] + bias) * scale);
            }
        }
}

// ------------- GEMM2: out = Ob @ WoT^T + bo (f32 out) -------------
__global__ __launch_bounds__(256) void k_gemm_out(const bf16* __restrict__ Ob, const bf16* __restrict__ WoT,
                                                  const float* __restrict__ bo, float* __restrict__ out) {
    __shared__ __align__(16) char As[16384];
    __shared__ __align__(16) char Bs[16384];
    int r0 = blockIdx.y * 128, c0 = blockIdx.x * 128;
    f32x4 acc[4][4] = {};
    gemm128_core(Ob, WoT, r0, c0, 1024, As, Bs, acc);
    int t = threadIdx.x, l = t & 63, w = t >> 6;
    int g = l >> 4, li = l & 15;
    int wr = w >> 1, wc = w & 1;
    #pragma unroll
    for (int m = 0; m < 4; ++m)
        #pragma unroll
        for (int n = 0; n < 4; ++n) {
            int col = c0 + wc * 64 + n * 16 + li;
            float bias = bo[col];
            #pragma unroll
            for (int r = 0; r < 4; ++r) {
                int row = r0 + wr * 64 + m * 16 + g * 4 + r;
                out[(size_t)row * 1024 + col] = acc[m][n][r] + bias;
            }
        }
}

// ------------- causal flash attention: Q,K [H][S][64] (Q pre-scaled), Vt [H][64][S] -> O [S][1024] bf16
__global__ __launch_bounds__(256) void k_attn(const bf16* __restrict__ Q, const bf16* __restrict__ K,
                                              const bf16* __restrict__ Vt, bf16* __restrict__ O) {
    __shared__ __align__(16) char Ks[8192];     // [64 t][64 hd] swizzled
    __shared__ __align__(16) char Vs[8192];     // [64 hd][64 t] swizzled
    __shared__ __align__(16) char Ps[4][4096];  // per-wave P [32 q][64 t] swizzled
    int h = blockIdx.y;
    int qb = (int)gridDim.x - 1 - (int)blockIdx.x;   // longest blocks first
    int q0 = qb * 128;
    int t = threadIdx.x, l = t & 63, w = t >> 6;
    int g = l >> 4, li = l & 15;
    const bf16* Qh = Q + (size_t)h * 4096 * 64;
    const bf16* Kh = K + (size_t)h * 4096 * 64;
    const bf16* Vh = Vt + (size_t)h * 64 * 4096;
    int qrow0 = q0 + w * 32;
    // hoist Q fragments to registers
    bf16x8 qf[2][2];
    #pragma unroll
    for (int m = 0; m < 2; ++m)
        #pragma unroll
        for (int kk = 0; kk < 2; ++kk)
            qf[m][kk] = *(const bf16x8*)(Qh + (size_t)(qrow0 + m * 16 + li) * 64 + kk * 32 + g * 8);
    f32x4 oacc[2][4] = {};
    float mrow[2][4], lrow[2][4];
    #pragma unroll
    for (int m = 0; m < 2; ++m)
        #pragma unroll
        for (int r = 0; r < 4; ++r) { mrow[m][r] = -1e30f; lrow[m][r] = 0.f; }
    int ntiles = qb * 2 + 2;
    for (int tt = 0; tt < ntiles; ++tt) {
        int t0 = tt * 64;
        uint4 rk[2], rv[2];
        #pragma unroll
        for (int i = 0; i < 2; ++i) {
            int c = i * 256 + t; int row = c >> 3, ch = c & 7;
            rk[i] = *(const uint4*)(Kh + (size_t)(t0 + row) * 64 + ch * 8);
            rv[i] = *(const uint4*)(Vh + (size_t)row * 4096 + t0 + ch * 8);
        }
        __syncthreads();   // previous tile's LDS reads done
        #pragma unroll
        for (int i = 0; i < 2; ++i) {
            int c = i * 256 + t; int row = c >> 3, ch = c & 7;
            int off = (row * 128 + ch * 16) ^ ((row & 7) << 4);
            *(uint4*)(Ks + off) = rk[i];
            *(uint4*)(Vs + off) = rv[i];
        }
        __syncthreads();
        if (t0 <= qrow0 + 31) {          // wave has at least one unmasked row in this tile
            // S = Q K^T  (S[q][t])
            f32x4 sacc[2][4] = {};
            #pragma unroll
            for (int n = 0; n < 4; ++n) {
                int krow = n * 16 + li;
                #pragma unroll
                for (int kk = 0; kk < 2; ++kk) {
                    bf16x8 kf = *(const bf16x8*)(Ks + ((krow * 128 + kk * 64 + g * 16) ^ ((krow & 7) << 4)));
                    #pragma unroll
                    for (int m = 0; m < 2; ++m)
                        sacc[m][n] = MFMA16(qf[m][kk], kf, sacc[m][n]);
                }
            }
            if (t0 + 63 > qrow0) {       // causal mask needed
                #pragma unroll
                for (int m = 0; m < 2; ++m)
                    #pragma unroll
                    for (int r = 0; r < 4; ++r) {
                        int rowq = qrow0 + m * 16 + g * 4 + r;
                        #pragma unroll
                        for (int n = 0; n < 4; ++n) {
                            int col = t0 + n * 16 + li;
                            if (col > rowq) sacc[m][n][r] = -1e30f;
                        }
                    }
            }
            // online softmax (rows owned by 16-lane groups; reduce over li)
            #pragma unroll
            for (int m = 0; m < 2; ++m) {
                float pm[4], al[4], rs[4];
                #pragma unroll
                for (int r = 0; r < 4; ++r) {
                    float v0 = fmaxf(fmaxf(sacc[m][0][r], sacc[m][1][r]),
                                     fmaxf(sacc[m][2][r], sacc[m][3][r]));
                    #pragma unroll
                    for (int s = 1; s < 16; s <<= 1) v0 = fmaxf(v0, __shfl_xor(v0, s));
                    float mn = fmaxf(mrow[m][r], v0);
                    al[r] = __expf(mrow[m][r] - mn);
                    mrow[m][r] = mn;
                    pm[r] = mn;
                    rs[r] = 0.f;
                }
                #pragma unroll
                for (int n = 0; n < 4; ++n)
                    #pragma unroll
                    for (int r = 0; r < 4; ++r) {
                        float p = __expf(sacc[m][n][r] - pm[r]);
                        sacc[m][n][r] = p;
                        rs[r] += p;
                    }
                #pragma unroll
                for (int r = 0; r < 4; ++r) {
                    float x = rs[r];
                    #pragma unroll
                    for (int s = 1; s < 16; s <<= 1) x += __shfl_xor(x, s);
                    lrow[m][r] = lrow[m][r] * al[r] + x;
                }
                #pragma unroll
                for (int n = 0; n < 4; ++n)
                    #pragma unroll
                    for (int r = 0; r < 4; ++r) oacc[m][n][r] *= al[r];
                // P -> LDS (bf16, swizzled) for PV re-layout
                #pragma unroll
                for (int n = 0; n < 4; ++n)
                    #pragma unroll
                    for (int r = 0; r < 4; ++r) {
                        int prow = m * 16 + g * 4 + r;
                        int off = (prow * 128 + (n * 16 + li) * 2) ^ ((prow & 7) << 4);
                        *(bf16*)(Ps[w] + off) = (bf16)sacc[m][n][r];
                    }
            }
            // O += P V
            #pragma unroll
            for (int kk = 0; kk < 2; ++kk) {
                bf16x8 pf[2];
                #pragma unroll
                for (int m = 0; m < 2; ++m) {
                    int prow = m * 16 + li;
                    pf[m] = *(const bf16x8*)(Ps[w] + ((prow * 128 + kk * 64 + g * 16) ^ ((prow & 7) << 4)));
                }
                #pragma unroll
                for (int n = 0; n < 4; ++n) {
                    int vrow = n * 16 + li;
                    bf16x8 vf = *(const bf16x8*)(Vs + ((vrow * 128 + kk * 64 + g * 16) ^ ((vrow & 7) << 4)));
                    #pragma unroll
                    for (int m = 0; m < 2; ++m)
                        oacc[m][n] = MFMA16(pf[m], vf, oacc[m][n]);
                }
            }
        }
    }
    // epilogue: normalize, write O [S][H*64]
    #pragma unroll
    for (int m = 0; m < 2; ++m) {
        float inv[4];
        #pragma unroll
        for (int r = 0; r < 4; ++r) inv[r] = 1.0f / lrow[m][r];
        #pragma unroll
        for (int n = 0; n < 4; ++n)
            #pragma unroll
            for (int r = 0; r < 4; ++r) {
                int row = qrow0 + m * 16 + g * 4 + r;
                O[(size_t)row * 1024 + h * 64 + n * 16 + li] = (bf16)(oacc[m][n][r] * inv[r]);
            }
    }
}

extern "C" void kernel_launch(void* const* d_in, const int* in_sizes, int n_in,
                              void* d_out, int out_size, void* d_ws, size_t ws_size,
                              hipStream_t stream) {
    const float* X    = (const float*)d_in[0];   // [1,4096,1024]
    const float* Wqkv = (const float*)d_in[1];   // [1024,3072]
    const float* bqkv = (const float*)d_in[2];   // [3072]
    const float* Wo   = (const float*)d_in[3];   // [1024,1024]
    const float* bo   = (const float*)d_in[4];   // [1024]
    float* out = (float*)d_out;

    char* ws = (char*)d_ws;
    const size_t MB = 1024 * 1024;
    bf16* Xb    = (bf16*)(ws);             //  8 MB [4096][1024]
    bf16* WqkvT = (bf16*)(ws + 8  * MB);   //  6 MB [3072][1024]
    bf16* WoT   = (bf16*)(ws + 14 * MB);   //  2 MB [1024][1024]
    bf16* Qb    = (bf16*)(ws + 16 * MB);   //  8 MB [16][4096][64]
    bf16* Kb    = (bf16*)(ws + 24 * MB);   //  8 MB [16][4096][64]
    bf16* Vb    = (bf16*)(ws + 32 * MB);   //  8 MB [16][4096][64]
    bf16* Vtb   = (bf16*)(ws + 40 * MB);   //  8 MB [16][64][4096]
    bf16* Ob    = (bf16*)(ws + 48 * MB);   //  8 MB [4096][1024]

    k_convX<<<2048, 256, 0, stream>>>(X, Xb);
    k_tconv<<<dim3(48, 16), 256, 0, stream>>>(Wqkv, WqkvT, 1024, 3072);
    k_tconv<<<dim3(16, 16), 256, 0, stream>>>(Wo, WoT, 1024, 1024);
    k_gemm_qkv<<<dim3(24, 32), 256, 0, stream>>>(Xb, WqkvT, bqkv, Qb, Kb, Vb);
    k_vtrans<<<dim3(64, 16), 256, 0, stream>>>(Vb, Vtb);
    k_attn<<<dim3(32, 16), 256, 0, stream>>>(Qb, Kb, Vtb, Ob);
    k_gemm_out<<<dim3(8, 32), 256, 0, stream>>>(Ob, WoT, bo, out);
}

// Round 2
// 215.270 us; speedup vs baseline: 2.0318x; 2.0318x over previous
//
#include <hip/hip_runtime.h>

typedef __bf16 bf16;
typedef __bf16 bf16x8 __attribute__((ext_vector_type(8)));
typedef float f32x4 __attribute__((ext_vector_type(4)));

#define MFMA16(a, b, c) __builtin_amdgcn_mfma_f32_16x16x32_bf16((a), (b), (c), 0, 0, 0)

typedef const __attribute__((address_space(1))) uint32_t glb_u32;
typedef __attribute__((address_space(3))) uint32_t lds_u32;
#define GLOAD16(gp, lp) __builtin_amdgcn_global_load_lds((glb_u32*)(gp), (lds_u32*)(lp), 16, 0, 0)

// ---------------- elementwise f32 -> bf16 (8 per thread) ----------------
__global__ __launch_bounds__(256) void k_convX(const float* __restrict__ in, bf16* __restrict__ out) {
    size_t i = ((size_t)blockIdx.x * 256 + threadIdx.x) * 8;
    float4 a = *(const float4*)(in + i);
    float4 b = *(const float4*)(in + i + 4);
    bf16 e[8];
    e[0] = (bf16)a.x; e[1] = (bf16)a.y; e[2] = (bf16)a.z; e[3] = (bf16)a.w;
    e[4] = (bf16)b.x; e[5] = (bf16)b.y; e[6] = (bf16)b.z; e[7] = (bf16)b.w;
    uint4 u; __builtin_memcpy(&u, e, 16);
    *(uint4*)(out + i) = u;
}

// ------------- transpose+convert: in f32 [R][C] -> out bf16 [C][R] -------------
__global__ __launch_bounds__(256) void k_tconv(const float* __restrict__ in, bf16* __restrict__ out,
                                               int R, int C) {
    __shared__ float tile[64][65];
    int bx = blockIdx.x, by = blockIdx.y;   // bx over C/64, by over R/64
    int t = threadIdx.x;
    for (int i = 0; i < 16; ++i) {
        int e = i * 256 + t; int r = e >> 6, c = e & 63;
        tile[r][c] = in[(size_t)(by * 64 + r) * C + bx * 64 + c];
    }
    __syncthreads();
    for (int i = 0; i < 16; ++i) {
        int e = i * 256 + t; int r = e >> 6, c = e & 63;
        out[(size_t)(bx * 64 + r) * R + by * 64 + c] = (bf16)tile[c][r];
    }
}

// ------------- V [H][S][64] -> Vt [H][64][S] -------------
__global__ __launch_bounds__(256) void k_vtrans(const bf16* __restrict__ V, bf16* __restrict__ Vt) {
    __shared__ bf16 tl[64][68];
    int t0 = blockIdx.x * 64;
    int h = blockIdx.y;
    int t = threadIdx.x;
    const bf16* Vh = V + (size_t)h * 4096 * 64;
    #pragma unroll
    for (int i = 0; i < 2; ++i) {
        int c = i * 256 + t; int row = c >> 3, ch = c & 7;
        uint4 v = *(const uint4*)(Vh + (size_t)(t0 + row) * 64 + ch * 8);
        bf16 e[8]; __builtin_memcpy(e, &v, 16);
        #pragma unroll
        for (int j = 0; j < 8; ++j) tl[row][ch * 8 + j] = e[j];
    }
    __syncthreads();
    bf16* Vth = Vt + (size_t)h * 64 * 4096;
    #pragma unroll
    for (int i = 0; i < 2; ++i) {
        int c = i * 256 + t; int d = c >> 3, tch = c & 7;
        bf16 e[8];
        #pragma unroll
        for (int j = 0; j < 8; ++j) e[j] = tl[tch * 8 + j][d];
        uint4 u; __builtin_memcpy(&u, e, 16);
        *(uint4*)(Vth + (size_t)d * 4096 + t0 + tch * 8) = u;
    }
}

// ------------- 128x128 bf16 GEMM core: A [*,Kd] rm, Bt [*,Kd] rm, BK=64 -------------
// LDS staged via global_load_lds (linear dest) with inverse-swizzled global source;
// reads use XOR swizzle byte ^= (row&7)<<4.
__device__ __forceinline__ void gemm128_core(const bf16* __restrict__ A, const bf16* __restrict__ Bt,
                                             int r0, int c0, int Kd, char* As, char* Bs,
                                             f32x4 (&acc)[4][4]) {
    int t = threadIdx.x, l = t & 63, w = t >> 6;
    int g = l >> 4, li = l & 15;
    int wr = w >> 1, wc = w & 1;
    for (int k0 = 0; k0 < Kd; k0 += 64) {
        __syncthreads();   // prior iteration's LDS reads complete
        #pragma unroll
        for (int i = 0; i < 4; ++i) {
            int slot = i * 256 + t;                 // 16B slot index 0..1023
            int row = slot >> 3;
            int ch  = (slot & 7) ^ (row & 7);       // inverse swizzle on source
            int base = (i * 256 + w * 64) * 16;     // wave-uniform LDS base
            GLOAD16(A  + (size_t)(r0 + row) * Kd + k0 + ch * 8, As + base);
            GLOAD16(Bt + (size_t)(c0 + row) * Kd + k0 + ch * 8, Bs + base);
        }
        __syncthreads();   // barrier drains vmcnt -> tiles visible
        #pragma unroll
        for (int kk = 0; kk < 2; ++kk) {
            bf16x8 af[4], bfr[4];
            #pragma unroll
            for (int m = 0; m < 4; ++m) {
                int row = wr * 64 + m * 16 + li;
                af[m] = *(const bf16x8*)(As + ((row * 128 + kk * 64 + g * 16) ^ ((row & 7) << 4)));
            }
            #pragma unroll
            for (int n = 0; n < 4; ++n) {
                int row = wc * 64 + n * 16 + li;
                bfr[n] = *(const bf16x8*)(Bs + ((row * 128 + kk * 64 + g * 16) ^ ((row & 7) << 4)));
            }
            #pragma unroll
            for (int m = 0; m < 4; ++m)
                #pragma unroll
                for (int n = 0; n < 4; ++n)
                    acc[m][n] = MFMA16(af[m], bfr[n], acc[m][n]);
        }
    }
}

// ------------- GEMM1: qkv = Xb @ WqkvT^T + bqkv; scatter to Q(scaled)/K/V [H][S][64] -------------
__global__ __launch_bounds__(256) void k_gemm_qkv(const bf16* __restrict__ Xb, const bf16* __restrict__ WqkvT,
                                                  const float* __restrict__ bqkv,
                                                  bf16* __restrict__ Q, bf16* __restrict__ K,
                                                  bf16* __restrict__ V) {
    __shared__ __align__(16) char As[16384];
    __shared__ __align__(16) char Bs[16384];
    int r0 = blockIdx.y * 128, c0 = blockIdx.x * 128;
    f32x4 acc[4][4] = {};
    gemm128_core(Xb, WqkvT, r0, c0, 1024, As, Bs, acc);
    int t = threadIdx.x, l = t & 63, w = t >> 6;
    int g = l >> 4, li = l & 15;
    int wr = w >> 1, wc = w & 1;
    int colbase = c0 + wc * 64;            // multiple of 64 => one head per wave-column
    int sec = colbase >> 10;               // 0=Q 1=K 2=V
    int head = (colbase & 1023) >> 6;
    bf16* dst = (sec == 0) ? Q : (sec == 1) ? K : V;
    float scale = (sec == 0) ? 0.125f : 1.0f;   // 1/sqrt(64) folded into Q
    #pragma unroll
    for (int m = 0; m < 4; ++m)
        #pragma unroll
        for (int n = 0; n < 4; ++n) {
            int hd = n * 16 + li;
            float bias = bqkv[colbase + hd];
            #pragma unroll
            for (int r = 0; r < 4; ++r) {
                int row = r0 + wr * 64 + m * 16 + g * 4 + r;
                dst[(size_t)(head * 4096 + row) * 64 + hd] = (bf16)((acc[m][n][r] + bias) * scale);
            }
        }
}

// ------------- GEMM2: out = Ob @ WoT^T + bo (f32 out) -------------
__global__ __launch_bounds__(256) void k_gemm_out(const bf16* __restrict__ Ob, const bf16* __restrict__ WoT,
                                                  const float* __restrict__ bo, float* __restrict__ out) {
    __shared__ __align__(16) char As[16384];
    __shared__ __align__(16) char Bs[16384];
    int r0 = blockIdx.y * 128, c0 = blockIdx.x * 128;
    f32x4 acc[4][4] = {};
    gemm128_core(Ob, WoT, r0, c0, 1024, As, Bs, acc);
    int t = threadIdx.x, l = t & 63, w = t >> 6;
    int g = l >> 4, li = l & 15;
    int wr = w >> 1, wc = w & 1;
    #pragma unroll
    for (int m = 0; m < 4; ++m)
        #pragma unroll
        for (int n = 0; n < 4; ++n) {
            int col = c0 + wc * 64 + n * 16 + li;
            float bias = bo[col];
            #pragma unroll
            for (int r = 0; r < 4; ++r) {
                int row = r0 + wr * 64 + m * 16 + g * 4 + r;
                out[(size_t)row * 1024 + col] = acc[m][n][r] + bias;
            }
        }
}

// ------------- causal flash attention, balanced q-tile pairs -------------
// Q,K [H][S][64] (Q pre-scaled), Vt [H][64][S] -> O [S][1024] bf16.
// QBLK=64, 4 waves x 16 rows. Block (p,h) does q-tiles p and 63-p: 65 KV-tiles const.
__global__ __launch_bounds__(256) void k_attn(const bf16* __restrict__ Q, const bf16* __restrict__ K,
                                              const bf16* __restrict__ Vt, bf16* __restrict__ O) {
    __shared__ __align__(16) char Ks[8192];     // [64 t][64 hd] swizzled
    __shared__ __align__(16) char Vs[8192];     // [64 hd][64 t] swizzled
    __shared__ __align__(16) char Ps[4][2048];  // per-wave P [16 q][64 t] swizzled
    int h = blockIdx.y;
    int p = blockIdx.x;                          // pair index 0..31
    int t = threadIdx.x, l = t & 63, w = t >> 6;
    int g = l >> 4, li = l & 15;
    const bf16* Qh = Q + (size_t)h * 4096 * 64;
    const bf16* Kh = K + (size_t)h * 4096 * 64;
    const bf16* Vh = Vt + (size_t)h * 64 * 4096;
    #pragma unroll 1
    for (int seg = 0; seg < 2; ++seg) {
        int qt = (seg == 0) ? p : 63 - p;        // q-tile index (QBLK=64)
        int q0 = qt * 64;
        int qrow0 = q0 + w * 16;
        // Q fragments (A-layout: row=li, k=kk*32+g*8)
        bf16x8 qf[2];
        #pragma unroll
        for (int kk = 0; kk < 2; ++kk)
            qf[kk] = *(const bf16x8*)(Qh + (size_t)(qrow0 + li) * 64 + kk * 32 + g * 8);
        f32x4 oacc[4] = {};
        float mrow[4], lrow[4];
        #pragma unroll
        for (int r = 0; r < 4; ++r) { mrow[r] = -1e30f; lrow[r] = 0.f; }
        int ntiles = qt + 1;
        for (int tt = 0; tt < ntiles; ++tt) {
            int t0 = tt * 64;
            __syncthreads();   // prior tile's LDS reads done
            #pragma unroll
            for (int i = 0; i < 2; ++i) {
                int slot = i * 256 + t;
                int row = slot >> 3;
                int ch  = (slot & 7) ^ (row & 7);
                int base = (i * 256 + w * 64) * 16;
                GLOAD16(Kh + (size_t)(t0 + row) * 64 + ch * 8, Ks + base);
                GLOAD16(Vh + (size_t)row * 4096 + t0 + ch * 8, Vs + base);
            }
            __syncthreads();
            // S = Q K^T  (S[q][t]); every wave has live rows in every tile (t0 <= qrow0)
            f32x4 sacc[4] = {};
            #pragma unroll
            for (int n = 0; n < 4; ++n) {
                int krow = n * 16 + li;
                #pragma unroll
                for (int kk = 0; kk < 2; ++kk) {
                    bf16x8 kf = *(const bf16x8*)(Ks + ((krow * 128 + kk * 64 + g * 16) ^ ((krow & 7) << 4)));
                    sacc[n] = MFMA16(qf[kk], kf, sacc[n]);
                }
            }
            if (t0 + 63 > qrow0) {       // causal mask (diagonal tile only)
                #pragma unroll
                for (int r = 0; r < 4; ++r) {
                    int rowq = qrow0 + g * 4 + r;
                    #pragma unroll
                    for (int n = 0; n < 4; ++n) {
                        int col = t0 + n * 16 + li;
                        if (col > rowq) sacc[n][r] = -1e30f;
                    }
                }
            }
            // online softmax (rows owned by 4-lane reg slots; reduce over 16 li lanes)
            float pm[4], al[4], rs[4];
            #pragma unroll
            for (int r = 0; r < 4; ++r) {
                float v0 = fmaxf(fmaxf(sacc[0][r], sacc[1][r]), fmaxf(sacc[2][r], sacc[3][r]));
                #pragma unroll
                for (int s = 1; s < 16; s <<= 1) v0 = fmaxf(v0, __shfl_xor(v0, s));
                float mn = fmaxf(mrow[r], v0);
                al[r] = __expf(mrow[r] - mn);
                mrow[r] = mn;
                pm[r] = mn;
                rs[r] = 0.f;
            }
            #pragma unroll
            for (int n = 0; n < 4; ++n)
                #pragma unroll
                for (int r = 0; r < 4; ++r) {
                    float pv = __expf(sacc[n][r] - pm[r]);
                    sacc[n][r] = pv;
                    rs[r] += pv;
                }
            #pragma unroll
            for (int r = 0; r < 4; ++r) {
                float x = rs[r];
                #pragma unroll
                for (int s = 1; s < 16; s <<= 1) x += __shfl_xor(x, s);
                lrow[r] = lrow[r] * al[r] + x;
            }
            #pragma unroll
            for (int n = 0; n < 4; ++n)
                #pragma unroll
                for (int r = 0; r < 4; ++r) oacc[n][r] *= al[r];
            // P -> LDS (bf16, swizzled) for PV re-layout
            #pragma unroll
            for (int n = 0; n < 4; ++n)
                #pragma unroll
                for (int r = 0; r < 4; ++r) {
                    int prow = g * 4 + r;
                    int off = (prow * 128 + (n * 16 + li) * 2) ^ ((prow & 7) << 4);
                    *(bf16*)(Ps[w] + off) = (bf16)sacc[n][r];
                }
            // O += P V
            #pragma unroll
            for (int kk = 0; kk < 2; ++kk) {
                bf16x8 pf = *(const bf16x8*)(Ps[w] + ((li * 128 + kk * 64 + g * 16) ^ ((li & 7) << 4)));
                #pragma unroll
                for (int n = 0; n < 4; ++n) {
                    int vrow = n * 16 + li;
                    bf16x8 vf = *(const bf16x8*)(Vs + ((vrow * 128 + kk * 64 + g * 16) ^ ((vrow & 7) << 4)));
                    oacc[n] = MFMA16(pf, vf, oacc[n]);
                }
            }
        }
        // epilogue: normalize, write O [S][H*64]
        float inv[4];
        #pragma unroll
        for (int r = 0; r < 4; ++r) inv[r] = 1.0f / lrow[r];
        #pragma unroll
        for (int n = 0; n < 4; ++n)
            #pragma unroll
            for (int r = 0; r < 4; ++r) {
                int row = qrow0 + g * 4 + r;
                O[(size_t)row * 1024 + h * 64 + n * 16 + li] = (bf16)(oacc[n][r] * inv[r]);
            }
    }
}

extern "C" void kernel_launch(void* const* d_in, const int* in_sizes, int n_in,
                              void* d_out, int out_size, void* d_ws, size_t ws_size,
                              hipStream_t stream) {
    const float* X    = (const float*)d_in[0];   // [1,4096,1024]
    const float* Wqkv = (const float*)d_in[1];   // [1024,3072]
    const float* bqkv = (const float*)d_in[2];   // [3072]
    const float* Wo   = (const float*)d_in[3];   // [1024,1024]
    const float* bo   = (const float*)d_in[4];   // [1024]
    float* out = (float*)d_out;

    char* ws = (char*)d_ws;
    const size_t MB = 1024 * 1024;
    bf16* Xb    = (bf16*)(ws);             //  8 MB [4096][1024]
    bf16* WqkvT = (bf16*)(ws + 8  * MB);   //  6 MB [3072][1024]
    bf16* WoT   = (bf16*)(ws + 14 * MB);   //  2 MB [1024][1024]
    bf16* Qb    = (bf16*)(ws + 16 * MB);   //  8 MB [16][4096][64]
    bf16* Kb    = (bf16*)(ws + 24 * MB);   //  8 MB [16][4096][64]
    bf16* Vb    = (bf16*)(ws + 32 * MB);   //  8 MB [16][4096][64]
    bf16* Vtb   = (bf16*)(ws + 40 * MB);   //  8 MB [16][64][4096]
    bf16* Ob    = (bf16*)(ws + 48 * MB);   //  8 MB [4096][1024]

    k_convX<<<2048, 256, 0, stream>>>(X, Xb);
    k_tconv<<<dim3(48, 16), 256, 0, stream>>>(Wqkv, WqkvT, 1024, 3072);
    k_tconv<<<dim3(16, 16), 256, 0, stream>>>(Wo, WoT, 1024, 1024);
    k_gemm_qkv<<<dim3(24, 32), 256, 0, stream>>>(Xb, WqkvT, bqkv, Qb, Kb, Vb);
    k_vtrans<<<dim3(64, 16), 256, 0, stream>>>(Vb, Vtb);
    k_attn<<<dim3(32, 16), 256, 0, stream>>>(Qb, Kb, Vtb, Ob);
    k_gemm_out<<<dim3(8, 32), 256, 0, stream>>>(Ob, WoT, bo, out);
}